// Round 9
// baseline (328.594 us; speedup 1.0000x reference)
//
#include <hip/hip_runtime.h>

#define N_NODES 100000
#define N_EDGES 1000000
#define D 64
#define NB 196        // buckets of 512 dst nodes: 196*512 = 100352 >= N_NODES
#define SUBCAP 1024   // per (bucket, sub) capacity; mean ~640, ~15 sigma safe
#define BSTAGE 6144   // per-bucket col stage; mean 5120, ~14 sigma safe
#define CHUNK 4096    // edges per phase-A block
#define ABLOCKS ((N_EDGES + CHUNK - 1) / CHUNK)   // 245
#define MSTRIDE 130   // u16 stride for mtT rows: 65 dwords -> conflict-free reads

// ---------------- phase A: block-local counting sort by dst bucket ----------------
__global__ void __launch_bounds__(256)
k_bucketA(const int* __restrict__ ei, int* __restrict__ subcur,
          int* __restrict__ pairs) {
    __shared__ int hist[256];
    __shared__ int sc[256];
    __shared__ int lpos[NB];
    __shared__ int lcur[NB];
    __shared__ int gbase[NB];
    __shared__ int stage[CHUNK];
    __shared__ int astage[CHUNK];
    int t = threadIdx.x, blk = blockIdx.x;
    int sub = blk & 7;
    int e0 = blk * CHUNK;
    int e1 = min(e0 + CHUNK, N_EDGES);
    int cnt = e1 - e0;

    hist[t] = 0;
    __syncthreads();
    for (int i = t; i < cnt; i += 256) {
        int d = ei[N_EDGES + e0 + i];
        atomicAdd(&hist[d >> 9], 1);
    }
    __syncthreads();
    int h = hist[t];
    sc[t] = h;
    __syncthreads();
    for (int off = 1; off < 256; off <<= 1) {
        int v = (t >= off) ? sc[t - off] : 0;
        __syncthreads();
        sc[t] += v;
        __syncthreads();
    }
    if (t < NB) {
        int excl = sc[t] - h;
        lpos[t] = excl;
        lcur[t] = excl;
        gbase[t] = (h > 0) ? atomicAdd(&subcur[(t << 3) | sub], h) : 0;
    }
    __syncthreads();
    for (int i = t; i < cnt; i += 256) {
        int s = ei[e0 + i];
        int d = ei[N_EDGES + e0 + i];
        int b = d >> 9;
        int p = atomicAdd(&lcur[b], 1);
        int o = gbase[b] + (p - lpos[b]);
        stage[p] = (s << 9) | (d & 511);
        astage[p] = (o < SUBCAP) ? (((b << 3) | sub) * SUBCAP + o) : -1;
    }
    __syncthreads();
    for (int i = t; i < cnt; i += 256) {
        int a = astage[i];
        if (a >= 0) pairs[a] = stage[i];
    }
}

// ---------------- bucket-level exclusive scan (1 block) ----------------
__global__ void k_bscan(const int* __restrict__ subcur, int* __restrict__ bucket_base) {
    __shared__ int tot[256];
    int t = threadIdx.x;
    int sum = 0;
    if (t < NB) {
        for (int s = 0; s < 8; s++) sum += min(subcur[t * 8 + s], SUBCAP);
    }
    tot[t] = sum;
    __syncthreads();
    for (int off = 1; off < 256; off <<= 1) {
        int v = (t >= off) ? tot[t - off] : 0;
        __syncthreads();
        tot[t] += v;
        __syncthreads();
    }
    if (t < NB) bucket_base[t] = (t == 0) ? 0 : tot[t - 1];
    if (t == NB - 1) bucket_base[NB] = tot[t];
}

// ---------------- phase B: per-bucket local counting sort ----------------
__global__ void __launch_bounds__(256)
k_bucketB(const int* __restrict__ subcur, const int* __restrict__ pairs,
          const int* __restrict__ bucket_base, int* __restrict__ col,
          int* __restrict__ row_start, float* __restrict__ invc) {
    __shared__ int ldeg[512];
    __shared__ int lpos[512];
    __shared__ int lcur[512];
    __shared__ int sc[256];
    __shared__ int cnt[8];
    __shared__ int stage[BSTAGE];
    int b = blockIdx.x, t = threadIdx.x;
    if (t < 8) cnt[t] = min(subcur[b * 8 + t], SUBCAP);
    for (int i = t; i < 512; i += 256) ldeg[i] = 0;
    __syncthreads();
    for (int s = 0; s < 8; s++) {
        int c = cnt[s];
        const int* base = pairs + (size_t)(b * 8 + s) * SUBCAP;
        for (int i = t; i < c; i += 256) atomicAdd(&ldeg[base[i] & 511], 1);
    }
    __syncthreads();
    int a0 = ldeg[2 * t], a1 = ldeg[2 * t + 1];
    sc[t] = a0 + a1;
    __syncthreads();
    for (int off = 1; off < 256; off <<= 1) {
        int v = (t >= off) ? sc[t - off] : 0;
        __syncthreads();
        sc[t] += v;
        __syncthreads();
    }
    int excl = (t == 0) ? 0 : sc[t - 1];
    lpos[2 * t] = excl;
    lpos[2 * t + 1] = excl + a0;
    lcur[2 * t] = excl;
    lcur[2 * t + 1] = excl + a0;
    __syncthreads();
    int bbase = bucket_base[b];
    int total = bucket_base[b + 1] - bbase;
    if (total > BSTAGE) total = BSTAGE;
    int n0 = b * 512;
    for (int i = t; i < 512; i += 256) {
        int n = n0 + i;
        if (n < N_NODES) {
            row_start[n] = bbase + lpos[i];
            int dg = ldeg[i];
            invc[n] = 1.0f / (float)(dg > 0 ? dg : 1);
        }
    }
    if (b == 0 && t == 0) row_start[N_NODES] = bucket_base[NB];
    for (int s = 0; s < 8; s++) {
        int c = cnt[s];
        const int* base = pairs + (size_t)(b * 8 + s) * SUBCAP;
        for (int i = t; i < c; i += 256) {
            int v = base[i];
            int p = atomicAdd(&lcur[v & 511], 1);
            if (p < BSTAGE) stage[p] = v >> 9;
        }
    }
    __syncthreads();
    for (int i = t; i < total; i += 256) col[bbase + i] = stage[i];
}

// ---------------- fused layer: mean-agg (LDS) + linear ----------------
// Block = 128 nodes. Phase 1: 16-lane-per-node float4 gather (x4 unroll),
// mean written to LDS as bf16 mtT[k][local] (stride 130 u16 = 65 dwords,
// conflict-free reads). Phase 2: lane = 2 nodes, wave = 16 ocs; weights in
// LDS unpadded (wave-uniform broadcast reads); per k: 2 u16 + 8 b128 LDS
// (~108 cyc) vs 64 FMA (128 cyc) -> VALU-bound. m never touches global.
__device__ __forceinline__ unsigned short f2b(float f) {
    unsigned u = __float_as_uint(f);
    unsigned r = u + 0x7FFFu + ((u >> 16) & 1u);   // RNE
    return (unsigned short)(r >> 16);
}

__global__ void __launch_bounds__(256)
k_layer(const float4* __restrict__ X4, const int* __restrict__ row_start,
        const int* __restrict__ col, const float* __restrict__ inv_cnt,
        const float* __restrict__ Wl, const float* __restrict__ Wr,
        const float* __restrict__ bias, float4* __restrict__ out4, int do_relu) {
    __shared__ float wlT[D * D];                 // [k][oc], unpadded (broadcast)
    __shared__ float wrT[D * D];
    __shared__ unsigned short mtT[D * MSTRIDE];  // [k][local], bf16
    int t = threadIdx.x;
    int nb = blockIdx.x * 128;

    // phase 0: stage transposed weights
    for (int i = t; i < D * D; i += 256) {
        int oc = i >> 6, k = i & 63;
        wlT[k * D + oc] = Wl[i];
        wrT[k * D + oc] = Wr[i];
    }

    // phase 1: aggregate 128 nodes, 16 lanes/node, 8 sequential batches
    int sub = t & 15;
    int g = t >> 4;                // 16 concurrent node-groups
    for (int b = 0; b < 8; b++) {
        int ln = b * 16 + g;       // local node 0..127
        int n = nb + ln;
        if (n < N_NODES) {
            int s = row_start[n];
            int e = row_start[n + 1];
            float4 acc = make_float4(0.f, 0.f, 0.f, 0.f);
            int j = s;
            for (; j + 4 <= e; j += 4) {
                int c0 = col[j + 0];
                int c1 = col[j + 1];
                int c2 = col[j + 2];
                int c3 = col[j + 3];
                float4 a = X4[(size_t)c0 * 16 + sub];
                float4 bq = X4[(size_t)c1 * 16 + sub];
                float4 c = X4[(size_t)c2 * 16 + sub];
                float4 d = X4[(size_t)c3 * 16 + sub];
                acc.x += (a.x + bq.x) + (c.x + d.x);
                acc.y += (a.y + bq.y) + (c.y + d.y);
                acc.z += (a.z + bq.z) + (c.z + d.z);
                acc.w += (a.w + bq.w) + (c.w + d.w);
            }
            for (; j < e; j++) {
                float4 a = X4[(size_t)col[j] * 16 + sub];
                acc.x += a.x; acc.y += a.y; acc.z += a.z; acc.w += a.w;
            }
            float ic = inv_cnt[n];
            mtT[(4 * sub + 0) * MSTRIDE + ln] = f2b(acc.x * ic);
            mtT[(4 * sub + 1) * MSTRIDE + ln] = f2b(acc.y * ic);
            mtT[(4 * sub + 2) * MSTRIDE + ln] = f2b(acc.z * ic);
            mtT[(4 * sub + 3) * MSTRIDE + ln] = f2b(acc.w * ic);
        }
    }
    __syncthreads();

    // phase 2: linear, lane = 2 nodes, wave = 16 output channels
    int lane = t & 63;
    int ocb = (t >> 6) << 4;
    int n0 = nb + lane;
    int n1 = nb + 64 + lane;
    bool v0 = n0 < N_NODES, v1 = n1 < N_NODES;
    int a0i = v0 ? n0 : N_NODES - 1;
    int a1i = v1 ? n1 : N_NODES - 1;
    const float4* xrow0 = X4 + (size_t)a0i * 16;
    const float4* xrow1 = X4 + (size_t)a1i * 16;

    float acc0[16], acc1[16];
#pragma unroll
    for (int o = 0; o < 16; o++) { acc0[o] = bias[ocb + o]; acc1[o] = acc0[o]; }

#pragma unroll 2
    for (int k4 = 0; k4 < D / 4; k4++) {
        float4 xv0 = xrow0[k4];
        float4 xv1 = xrow1[k4];
        const float* xp0 = (const float*)&xv0;
        const float* xp1 = (const float*)&xv1;
#pragma unroll
        for (int j = 0; j < 4; j++) {
            int k = (k4 << 2) + j;
            float m0 = __uint_as_float((unsigned)mtT[k * MSTRIDE + lane] << 16);
            float m1 = __uint_as_float((unsigned)mtT[k * MSTRIDE + 64 + lane] << 16);
            float x0 = xp0[j], x1 = xp1[j];
            const float4* wl4 = (const float4*)&wlT[k * D + ocb];
            const float4* wr4 = (const float4*)&wrT[k * D + ocb];
#pragma unroll
            for (int og = 0; og < 4; og++) {
                float4 wlv = wl4[og];
                float4 wrv = wr4[og];
                acc0[og * 4 + 0] = fmaf(m0, wlv.x, fmaf(x0, wrv.x, acc0[og * 4 + 0]));
                acc0[og * 4 + 1] = fmaf(m0, wlv.y, fmaf(x0, wrv.y, acc0[og * 4 + 1]));
                acc0[og * 4 + 2] = fmaf(m0, wlv.z, fmaf(x0, wrv.z, acc0[og * 4 + 2]));
                acc0[og * 4 + 3] = fmaf(m0, wlv.w, fmaf(x0, wrv.w, acc0[og * 4 + 3]));
                acc1[og * 4 + 0] = fmaf(m1, wlv.x, fmaf(x1, wrv.x, acc1[og * 4 + 0]));
                acc1[og * 4 + 1] = fmaf(m1, wlv.y, fmaf(x1, wrv.y, acc1[og * 4 + 1]));
                acc1[og * 4 + 2] = fmaf(m1, wlv.z, fmaf(x1, wrv.z, acc1[og * 4 + 2]));
                acc1[og * 4 + 3] = fmaf(m1, wlv.w, fmaf(x1, wrv.w, acc1[og * 4 + 3]));
            }
        }
    }

    if (do_relu) {
#pragma unroll
        for (int o = 0; o < 16; o++) {
            acc0[o] = fmaxf(acc0[o], 0.f);
            acc1[o] = fmaxf(acc1[o], 0.f);
        }
    }
    if (v0) {
        float4* orow = out4 + (size_t)n0 * 16 + (ocb >> 2);
#pragma unroll
        for (int og = 0; og < 4; og++)
            orow[og] = make_float4(acc0[og * 4 + 0], acc0[og * 4 + 1],
                                   acc0[og * 4 + 2], acc0[og * 4 + 3]);
    }
    if (v1) {
        float4* orow = out4 + (size_t)n1 * 16 + (ocb >> 2);
#pragma unroll
        for (int og = 0; og < 4; og++)
            orow[og] = make_float4(acc1[og * 4 + 0], acc1[og * 4 + 1],
                                   acc1[og * 4 + 2], acc1[og * 4 + 3]);
    }
}

// ---------------- launch ----------------
extern "C" void kernel_launch(void* const* d_in, const int* in_sizes, int n_in,
                              void* d_out, int out_size, void* d_ws, size_t ws_size,
                              hipStream_t stream) {
    const float* x   = (const float*)d_in[0];
    const int*   ei  = (const int*)d_in[1];
    const float* W1l = (const float*)d_in[2];
    const float* b1  = (const float*)d_in[3];
    const float* W1r = (const float*)d_in[4];
    const float* W2l = (const float*)d_in[5];
    const float* b2  = (const float*)d_in[6];
    const float* W2r = (const float*)d_in[7];
    float* out = (float*)d_out;

    char* ws = (char*)d_ws;
    size_t off = 0;
    auto alloc = [&](size_t bytes) -> char* {
        char* p = ws + off;
        off = (off + bytes + 255) & ~(size_t)255;
        return p;
    };
    int*   row_start   = (int*)alloc((size_t)(N_NODES + 1) * 4);
    int*   col         = (int*)alloc((size_t)N_EDGES * 4);
    float* invc        = (float*)alloc((size_t)N_NODES * 4);
    int*   subcur      = (int*)alloc((size_t)NB * 8 * 4);
    int*   bucket_base = (int*)alloc((size_t)(NB + 1) * 4);
    int*   pairs       = (int*)alloc((size_t)NB * 8 * SUBCAP * 4);
    float* hbuf        = (float*)alloc((size_t)N_NODES * D * 4);

    // CSR build via two-phase bucket sort (dense writes, low atomic contention)
    hipMemsetAsync(subcur, 0, (size_t)NB * 8 * 4, stream);
    k_bucketA<<<ABLOCKS, 256, 0, stream>>>(ei, subcur, pairs);
    k_bscan<<<1, 256, 0, stream>>>(subcur, bucket_base);
    k_bucketB<<<NB, 256, 0, stream>>>(subcur, pairs, bucket_base, col, row_start, invc);

    const int layer_blocks = (N_NODES + 127) / 128;   // 128 nodes per block

    // layer 1: h = relu(mean_agg(x)*W1l^T + x*W1r^T + b1)
    k_layer<<<layer_blocks, 256, 0, stream>>>((const float4*)x, row_start, col, invc,
                                              W1l, W1r, b1, (float4*)hbuf, 1);
    // layer 2: out = mean_agg(h)*W2l^T + h*W2r^T + b2
    k_layer<<<layer_blocks, 256, 0, stream>>>((const float4*)hbuf, row_start, col, invc,
                                              W2l, W2r, b2, (float4*)out, 0);
}

// Round 11
// 259.645 us; speedup vs baseline: 1.2655x; 1.2655x over previous
//
#include <hip/hip_runtime.h>

#define N_NODES 100000
#define N_EDGES 1000000
#define D 64
#define NB 196        // buckets of 512 dst nodes: 196*512 = 100352 >= N_NODES
#define SUBCAP 1024   // per (bucket, sub) capacity; mean ~640, ~15 sigma safe
#define BSTAGE 6144   // per-bucket col stage; mean 5120, ~14 sigma safe
#define CHUNK 4096    // edges per phase-A block
#define ABLOCKS ((N_EDGES + CHUNK - 1) / CHUNK)   // 245
#define WROW 68       // LDS weight row stride (floats)

// bf16 helpers (pairing contract: pack2 low ushort = first element;
// blo reads low ushort, bhi reads high ushort)
__device__ __forceinline__ unsigned short f2b(float f) {
    unsigned u = __float_as_uint(f);
    unsigned r = u + 0x7FFFu + ((u >> 16) & 1u);   // RNE
    return (unsigned short)(r >> 16);
}
__device__ __forceinline__ float blo(unsigned u) {
    return __uint_as_float(u << 16);
}
__device__ __forceinline__ float bhi(unsigned u) {
    return __uint_as_float(u & 0xFFFF0000u);
}
__device__ __forceinline__ unsigned pack2(float a, float b) {
    return (unsigned)f2b(a) | ((unsigned)f2b(b) << 16);
}

// ---------------- phase A: block-local counting sort by dst bucket ----------------
__global__ void __launch_bounds__(256)
k_bucketA(const int* __restrict__ ei, int* __restrict__ subcur,
          int* __restrict__ pairs) {
    __shared__ int hist[256];
    __shared__ int sc[256];
    __shared__ int lpos[NB];
    __shared__ int lcur[NB];
    __shared__ int gbase[NB];
    __shared__ int stage[CHUNK];
    __shared__ int astage[CHUNK];
    int t = threadIdx.x, blk = blockIdx.x;
    int sub = blk & 7;
    int e0 = blk * CHUNK;
    int e1 = min(e0 + CHUNK, N_EDGES);
    int cnt = e1 - e0;

    hist[t] = 0;
    __syncthreads();
    for (int i = t; i < cnt; i += 256) {
        int d = ei[N_EDGES + e0 + i];
        atomicAdd(&hist[d >> 9], 1);
    }
    __syncthreads();
    int h = hist[t];
    sc[t] = h;
    __syncthreads();
    for (int off = 1; off < 256; off <<= 1) {
        int v = (t >= off) ? sc[t - off] : 0;
        __syncthreads();
        sc[t] += v;
        __syncthreads();
    }
    if (t < NB) {
        int excl = sc[t] - h;
        lpos[t] = excl;
        lcur[t] = excl;
        gbase[t] = (h > 0) ? atomicAdd(&subcur[(t << 3) | sub], h) : 0;
    }
    __syncthreads();
    for (int i = t; i < cnt; i += 256) {
        int s = ei[e0 + i];
        int d = ei[N_EDGES + e0 + i];
        int b = d >> 9;
        int p = atomicAdd(&lcur[b], 1);
        int o = gbase[b] + (p - lpos[b]);
        stage[p] = (s << 9) | (d & 511);
        astage[p] = (o < SUBCAP) ? (((b << 3) | sub) * SUBCAP + o) : -1;
    }
    __syncthreads();
    for (int i = t; i < cnt; i += 256) {
        int a = astage[i];
        if (a >= 0) pairs[a] = stage[i];
    }
}

// ---------------- bucket-level exclusive scan (1 block) ----------------
__global__ void k_bscan(const int* __restrict__ subcur, int* __restrict__ bucket_base) {
    __shared__ int tot[256];
    int t = threadIdx.x;
    int sum = 0;
    if (t < NB) {
        for (int s = 0; s < 8; s++) sum += min(subcur[t * 8 + s], SUBCAP);
    }
    tot[t] = sum;
    __syncthreads();
    for (int off = 1; off < 256; off <<= 1) {
        int v = (t >= off) ? tot[t - off] : 0;
        __syncthreads();
        tot[t] += v;
        __syncthreads();
    }
    if (t < NB) bucket_base[t] = (t == 0) ? 0 : tot[t - 1];
    if (t == NB - 1) bucket_base[NB] = tot[t];
}

// ---------------- phase B: per-bucket local counting sort ----------------
__global__ void __launch_bounds__(256)
k_bucketB(const int* __restrict__ subcur, const int* __restrict__ pairs,
          const int* __restrict__ bucket_base, int* __restrict__ col,
          int* __restrict__ row_start, float* __restrict__ invc) {
    __shared__ int ldeg[512];
    __shared__ int lpos[512];
    __shared__ int lcur[512];
    __shared__ int sc[256];
    __shared__ int cnt[8];
    __shared__ int stage[BSTAGE];
    int b = blockIdx.x, t = threadIdx.x;
    if (t < 8) cnt[t] = min(subcur[b * 8 + t], SUBCAP);
    for (int i = t; i < 512; i += 256) ldeg[i] = 0;
    __syncthreads();
    for (int s = 0; s < 8; s++) {
        int c = cnt[s];
        const int* base = pairs + (size_t)(b * 8 + s) * SUBCAP;
        for (int i = t; i < c; i += 256) atomicAdd(&ldeg[base[i] & 511], 1);
    }
    __syncthreads();
    int a0 = ldeg[2 * t], a1 = ldeg[2 * t + 1];
    sc[t] = a0 + a1;
    __syncthreads();
    for (int off = 1; off < 256; off <<= 1) {
        int v = (t >= off) ? sc[t - off] : 0;
        __syncthreads();
        sc[t] += v;
        __syncthreads();
    }
    int excl = (t == 0) ? 0 : sc[t - 1];
    lpos[2 * t] = excl;
    lpos[2 * t + 1] = excl + a0;
    lcur[2 * t] = excl;
    lcur[2 * t + 1] = excl + a0;
    __syncthreads();
    int bbase = bucket_base[b];
    int total = bucket_base[b + 1] - bbase;
    if (total > BSTAGE) total = BSTAGE;
    int n0 = b * 512;
    for (int i = t; i < 512; i += 256) {
        int n = n0 + i;
        if (n < N_NODES) {
            row_start[n] = bbase + lpos[i];
            int dg = ldeg[i];
            invc[n] = 1.0f / (float)(dg > 0 ? dg : 1);
        }
    }
    if (b == 0 && t == 0) row_start[N_NODES] = bucket_base[NB];
    for (int s = 0; s < 8; s++) {
        int c = cnt[s];
        const int* base = pairs + (size_t)(b * 8 + s) * SUBCAP;
        for (int i = t; i < c; i += 256) {
            int v = base[i];
            int p = atomicAdd(&lcur[v & 511], 1);
            if (p < BSTAGE) stage[p] = v >> 9;
        }
    }
    __syncthreads();
    for (int i = t; i < total; i += 256) col[bbase + i] = stage[i];
}

// ---------------- cast: fp32 rows -> bf16 rows ----------------
__global__ void __launch_bounds__(256)
k_cast(const float4* __restrict__ X4, uint4* __restrict__ Xb) {
    int i = blockIdx.x * 256 + threadIdx.x;   // one per 8 floats
    if (i >= N_NODES * D / 8) return;
    float4 a = X4[2 * i];
    float4 b = X4[2 * i + 1];
    uint4 o;
    o.x = pack2(a.x, a.y);
    o.y = pack2(a.z, a.w);
    o.z = pack2(b.x, b.y);
    o.w = pack2(b.z, b.w);
    Xb[i] = o;
}

// ---------------- aggregation: mean over in-neighbors (bf16 in, fp32 out) -------
// 8 lanes/node, uint4 (16B = 8 bf16) per lane: row = 128B = 2 lines (fp32 was 4).
// 8 nodes/wave x 4 unroll = 32 independent gather chains/wave. fp32 accumulate,
// fp32 m out (feeds the proven fp32 k_linear unchanged).
__global__ void __launch_bounds__(256)
k_agg_b(const uint4* __restrict__ Xb, const int* __restrict__ row_start,
        const int* __restrict__ col, const float* __restrict__ inv_cnt,
        float4* __restrict__ M4) {
    int t = blockIdx.x * 256 + threadIdx.x;
    int sub = t & 7;           // which 8-element chunk of the row
    int n = t >> 3;            // node id
    if (n >= N_NODES) return;
    int s = row_start[n];
    int e = row_start[n + 1];
    float a[8];
#pragma unroll
    for (int i = 0; i < 8; i++) a[i] = 0.f;
    int j = s;
    for (; j + 4 <= e; j += 4) {
        int c0 = col[j + 0];
        int c1 = col[j + 1];
        int c2 = col[j + 2];
        int c3 = col[j + 3];
        uint4 q0 = Xb[(size_t)c0 * 8 + sub];
        uint4 q1 = Xb[(size_t)c1 * 8 + sub];
        uint4 q2 = Xb[(size_t)c2 * 8 + sub];
        uint4 q3 = Xb[(size_t)c3 * 8 + sub];
        const unsigned* u0 = (const unsigned*)&q0;
        const unsigned* u1 = (const unsigned*)&q1;
        const unsigned* u2 = (const unsigned*)&q2;
        const unsigned* u3 = (const unsigned*)&q3;
#pragma unroll
        for (int w = 0; w < 4; w++) {
            a[2 * w + 0] += (blo(u0[w]) + blo(u1[w])) + (blo(u2[w]) + blo(u3[w]));
            a[2 * w + 1] += (bhi(u0[w]) + bhi(u1[w])) + (bhi(u2[w]) + bhi(u3[w]));
        }
    }
    for (; j < e; j++) {
        uint4 q = Xb[(size_t)col[j] * 8 + sub];
        const unsigned* u = (const unsigned*)&q;
#pragma unroll
        for (int w = 0; w < 4; w++) {
            a[2 * w + 0] += blo(u[w]);
            a[2 * w + 1] += bhi(u[w]);
        }
    }
    float ic = inv_cnt[n];
    M4[(size_t)n * 16 + sub * 2 + 0] = make_float4(a[0] * ic, a[1] * ic,
                                                   a[2] * ic, a[3] * ic);
    M4[(size_t)n * 16 + sub * 2 + 1] = make_float4(a[4] * ic, a[5] * ic,
                                                   a[6] * ic, a[7] * ic);
}

// ---------------- fused linear (Round 6 verbatim, proven) ----------------
// lane = node (64/block), wave = 16 ocs; weights in LDS transposed (stride 68),
// wave-uniform ds_read_b128 broadcast.
__global__ void __launch_bounds__(256)
k_linear(const float4* __restrict__ Ma4, const float4* __restrict__ Xa4,
         const float* __restrict__ Wl, const float* __restrict__ Wr,
         const float* __restrict__ bias, float4* __restrict__ out4, int do_relu) {
    __shared__ float wlT[D * WROW];
    __shared__ float wrT[D * WROW];
    int t = threadIdx.x;
    for (int i = t; i < D * D; i += 256) {
        int oc = i >> 6, k = i & 63;
        wlT[k * WROW + oc] = Wl[i];
        wrT[k * WROW + oc] = Wr[i];
    }
    __syncthreads();

    int lane = t & 63;
    int ocb = (t >> 6) * 16;
    int n = blockIdx.x * 64 + lane;
    if (n >= N_NODES) return;

    const float4* mrow = Ma4 + (size_t)n * (D / 4);
    const float4* xrow = Xa4 + (size_t)n * (D / 4);

    float acc[16];
#pragma unroll
    for (int o = 0; o < 16; o++) acc[o] = bias[ocb + o];

#pragma unroll 4
    for (int k4 = 0; k4 < D / 4; k4++) {
        float4 mv = mrow[k4];
        float4 xv = xrow[k4];
        const float* mp = (const float*)&mv;
        const float* xp = (const float*)&xv;
#pragma unroll
        for (int j = 0; j < 4; j++) {
            int k = k4 * 4 + j;
            const float4* wl4 = (const float4*)&wlT[k * WROW + ocb];
            const float4* wr4 = (const float4*)&wrT[k * WROW + ocb];
            float mj = mp[j];
            float xj = xp[j];
#pragma unroll
            for (int og = 0; og < 4; og++) {
                float4 wlv = wl4[og];
                float4 wrv = wr4[og];
                acc[og * 4 + 0] = fmaf(mj, wlv.x, fmaf(xj, wrv.x, acc[og * 4 + 0]));
                acc[og * 4 + 1] = fmaf(mj, wlv.y, fmaf(xj, wrv.y, acc[og * 4 + 1]));
                acc[og * 4 + 2] = fmaf(mj, wlv.z, fmaf(xj, wrv.z, acc[og * 4 + 2]));
                acc[og * 4 + 3] = fmaf(mj, wlv.w, fmaf(xj, wrv.w, acc[og * 4 + 3]));
            }
        }
    }

    if (do_relu) {
#pragma unroll
        for (int o = 0; o < 16; o++) acc[o] = fmaxf(acc[o], 0.f);
    }
    float4* orow = out4 + (size_t)n * (D / 4) + (ocb >> 2);
#pragma unroll
    for (int og = 0; og < 4; og++) {
        orow[og] = make_float4(acc[og * 4 + 0], acc[og * 4 + 1],
                               acc[og * 4 + 2], acc[og * 4 + 3]);
    }
}

// ---------------- launch ----------------
extern "C" void kernel_launch(void* const* d_in, const int* in_sizes, int n_in,
                              void* d_out, int out_size, void* d_ws, size_t ws_size,
                              hipStream_t stream) {
    const float* x   = (const float*)d_in[0];
    const int*   ei  = (const int*)d_in[1];
    const float* W1l = (const float*)d_in[2];
    const float* b1  = (const float*)d_in[3];
    const float* W1r = (const float*)d_in[4];
    const float* W2l = (const float*)d_in[5];
    const float* b2  = (const float*)d_in[6];
    const float* W2r = (const float*)d_in[7];
    float* out = (float*)d_out;

    char* ws = (char*)d_ws;
    size_t off = 0;
    auto alloc = [&](size_t bytes) -> char* {
        char* p = ws + off;
        off = (off + bytes + 255) & ~(size_t)255;
        return p;
    };
    int*   row_start   = (int*)alloc((size_t)(N_NODES + 1) * 4);
    int*   col         = (int*)alloc((size_t)N_EDGES * 4);
    float* invc        = (float*)alloc((size_t)N_NODES * 4);
    int*   subcur      = (int*)alloc((size_t)NB * 8 * 4);
    int*   bucket_base = (int*)alloc((size_t)(NB + 1) * 4);
    // shared region: pairs (6.4MB, dead after bucketB) -> xb (dead after agg1)
    // -> hb2. 12.8MB total.
    char*  region      = alloc((size_t)N_NODES * D * 2);
    float* mbuf        = (float*)alloc((size_t)N_NODES * D * 4);
    float* hbuf        = (float*)alloc((size_t)N_NODES * D * 4);
    int*   pairs = (int*)region;
    uint4* xb    = (uint4*)region;

    // CSR build via two-phase bucket sort
    hipMemsetAsync(subcur, 0, (size_t)NB * 8 * 4, stream);
    k_bucketA<<<ABLOCKS, 256, 0, stream>>>(ei, subcur, pairs);
    k_bscan<<<1, 256, 0, stream>>>(subcur, bucket_base);
    k_bucketB<<<NB, 256, 0, stream>>>(subcur, pairs, bucket_base, col, row_start, invc);

    const int cast_blocks = (N_NODES * D / 8 + 255) / 256;
    const int agg_blocks  = (N_NODES * 8 + 255) / 256;   // 8 lanes per node
    const int lin_blocks  = (N_NODES + 63) / 64;         // 64 nodes per block

    // layer 1: m1 = mean_agg(bf16(x)); h = relu(m1*W1l^T + x*W1r^T + b1)
    k_cast<<<cast_blocks, 256, 0, stream>>>((const float4*)x, xb);
    k_agg_b<<<agg_blocks, 256, 0, stream>>>(xb, row_start, col, invc, (float4*)mbuf);
    k_linear<<<lin_blocks, 256, 0, stream>>>((const float4*)mbuf, (const float4*)x,
                                             W1l, W1r, b1, (float4*)hbuf, 1);
    // layer 2: m2 = mean_agg(bf16(h)); out = m2*W2l^T + h*W2r^T + b2
    k_cast<<<cast_blocks, 256, 0, stream>>>((const float4*)hbuf, xb);
    k_agg_b<<<agg_blocks, 256, 0, stream>>>(xb, row_start, col, invc, (float4*)mbuf);
    k_linear<<<lin_blocks, 256, 0, stream>>>((const float4*)mbuf, (const float4*)hbuf,
                                             W2l, W2r, b2, (float4*)out, 0);
}